// Round 6
// baseline (226.903 us; speedup 1.0000x reference)
//
#include <hip/hip_runtime.h>
#include <stdint.h>

#define BINS 4096            // 64 * 64
#define ABLOCKS 4096
#define ATHREADS 256
#define I4_PER_BLOCK 1024    // int4s per array per block (4096 events/block)
#define I4_PER_THREAD (I4_PER_BLOCK / ATHREADS)   // 4

typedef __attribute__((address_space(3))) void       lds_void;
typedef const __attribute__((address_space(1))) void glob_void;

// out[i] = transitions_in[i] for i < bins; out[bins] = total_in + n_events
__global__ void topo_init_kernel(const float* __restrict__ transitions,
                                 const float* __restrict__ total,
                                 float* __restrict__ out,
                                 float n_events_f, int bins) {
    int i = blockIdx.x * blockDim.x + threadIdx.x;
    if (i < bins) out[i] = transitions[i];
    if (i == 0) out[bins] = total[0] + n_events_f;
}

// Async-staged histogram: each block DMAs its whole 4096-event slice (32 KB)
// into LDS via global_load_lds (no VGPR-limited MLP — requests queue freely),
// then bins from LDS. Requires n == ABLOCKS * I4_PER_BLOCK * 4.
__global__ void __launch_bounds__(ATHREADS)
topo_hist_async(const int* __restrict__ prev,
                const int* __restrict__ curr,
                float* __restrict__ out) {
    __shared__ unsigned h[BINS];          // 16 KB
    __shared__ int4 sp[I4_PER_BLOCK];     // 16 KB staged prev
    __shared__ int4 sc[I4_PER_BLOCK];     // 16 KB staged curr

    const int t = threadIdx.x;
    const int4* __restrict__ p4 = (const int4*)prev + (size_t)blockIdx.x * I4_PER_BLOCK;
    const int4* __restrict__ c4 = (const int4*)curr + (size_t)blockIdx.x * I4_PER_BLOCK;

    // Issue all staging DMA up front: 8 global_load_lds_dwordx4 per thread-slot,
    // 32 KB per block in flight. LDS dst is wave-uniform base + lane*16:
    // lptr = s? + k*ATHREADS + t gives lane0-uniform base per wave. Global addr
    // is lane-contiguous 16 B — matches the lane*16 placement exactly.
#pragma unroll
    for (int k = 0; k < I4_PER_THREAD; ++k) {
        __builtin_amdgcn_global_load_lds((glob_void*)(p4 + k * ATHREADS + t),
                                         (lds_void*)(sp + k * ATHREADS + t),
                                         16, 0, 0);
        __builtin_amdgcn_global_load_lds((glob_void*)(c4 + k * ATHREADS + t),
                                         (lds_void*)(sc + k * ATHREADS + t),
                                         16, 0, 0);
    }

    // Zero the histogram while the DMA is in flight (disjoint LDS region).
    for (int i = t; i < BINS; i += ATHREADS) h[i] = 0u;
    __syncthreads();   // drains vmcnt (staged data visible) + hist zeroed

    // Bin from LDS: ds_read_b128 at lane-sequential addresses (conflict-free
    // pattern), then LDS atomics.
#pragma unroll
    for (int k = 0; k < I4_PER_THREAD; ++k) {
        int4 p = sp[k * ATHREADS + t];
        int4 c = sc[k * ATHREADS + t];
        atomicAdd(&h[(p.x << 6) | c.x], 1u);
        atomicAdd(&h[(p.y << 6) | c.y], 1u);
        atomicAdd(&h[(p.z << 6) | c.z], 1u);
        atomicAdd(&h[(p.w << 6) | c.w], 1u);
    }

    __syncthreads();
    for (int i = t; i < BINS; i += ATHREADS) {
        unsigned cnt = h[i];
        if (cnt) atomicAdd(&out[i], (float)cnt);
    }
}

// Fallback for arbitrary n (predicated, grid-stride).
__global__ void __launch_bounds__(512)
topo_hist_generic(const int* __restrict__ prev,
                  const int* __restrict__ curr,
                  float* __restrict__ out, int n) {
    __shared__ unsigned h[BINS];
    for (int i = threadIdx.x; i < BINS; i += 512) h[i] = 0u;
    __syncthreads();

    const int tid = blockIdx.x * 512 + threadIdx.x;
    const int stride = gridDim.x * 512;
    for (int i = tid; i < n; i += stride)
        atomicAdd(&h[(prev[i] << 6) | curr[i]], 1u);

    __syncthreads();
    for (int i = threadIdx.x; i < BINS; i += 512) {
        unsigned cnt = h[i];
        if (cnt) atomicAdd(&out[i], (float)cnt);
    }
}

extern "C" void kernel_launch(void* const* d_in, const int* in_sizes, int n_in,
                              void* d_out, int out_size, void* d_ws, size_t ws_size,
                              hipStream_t stream) {
    const int*   prev        = (const int*)d_in[0];
    const int*   curr        = (const int*)d_in[1];
    const float* transitions = (const float*)d_in[2];
    const float* total       = (const float*)d_in[3];
    float* out = (float*)d_out;

    const int n    = in_sizes[0];
    const int bins = in_sizes[2];   // 4096

    // 1) initialize output: copy transitions input, set total = total_in + n
    int init_blocks = (bins + 1 + 255) / 256;
    topo_init_kernel<<<init_blocks, 256, 0, stream>>>(transitions, total, out,
                                                      (float)n, bins);

    const long long exact_n = (long long)ABLOCKS * I4_PER_BLOCK * 4;
    if (bins == BINS && (long long)n == exact_n) {
        topo_hist_async<<<ABLOCKS, ATHREADS, 0, stream>>>(prev, curr, out);
    } else {
        topo_hist_generic<<<1024, 512, 0, stream>>>(prev, curr, out, n);
    }
}

// Round 7
// 172.015 us; speedup vs baseline: 1.3191x; 1.3191x over previous
//
#include <hip/hip_runtime.h>

#define BINS 4096            // 64 * 64
#define HB 1024              // hist blocks
#define HT 512               // hist threads (8 waves)
#define NWAVE (HT / 64)      // 8
#define PT 8                 // int4-pairs per thread: 1024*512*8*4 = 16,777,216

#define RED_THREADS 256
#define RED_SPLITS 32        // each reduce block sums 1024/32 = 32 rows

// out[i] = transitions_in[i] for i < bins; out[bins] = total_in + n_events
__global__ void topo_init_kernel(const float* __restrict__ transitions,
                                 const float* __restrict__ total,
                                 float* __restrict__ out,
                                 float n_events_f, int bins) {
    int i = blockIdx.x * blockDim.x + threadIdx.x;
    if (i < bins) out[i] = transitions[i];
    if (i == 0) out[bins] = total[0] + n_events_f;
}

// Atomic-free histogram: per-wave u8 sub-histograms + claim-based intra-wave
// dedup using only plain DS reads/writes (LDS atomic RMW unit measured at
// ~112 cy/wave-op is the R1-R6 wall; plain scattered DS ops run ~11 cy).
//
// Claim protocol per 4-event batch: all undone lanes write claim[bin]=tid
// (4 write instrs), then read back (4 read instrs). Reads follow ALL writes in
// program order, so per slot exactly one lane sees its own tid -> unique
// winner per round. Winners do a plain u8 RMW on THEIR wave's cell (distinct
// bins -> distinct dwords within the wave, via the swizzle; cross-wave writes
// to a shared dword are separate pipeline slots with byte enables). Losers
// retry; every contended slot crowns >=1 winner per round -> terminates.
__global__ void __launch_bounds__(HT)
topo_hist_claim(const int* __restrict__ prev, const int* __restrict__ curr,
                unsigned* __restrict__ ws) {
    __shared__ volatile unsigned claimv[BINS];    // 16 KB; no init needed:
                                                  // always write-before-read
    __shared__ unsigned char h8[NWAVE * BINS];    // 32 KB; idx = b*8+((b+w)&7)

    const int t = threadIdx.x;
    const unsigned wave = (unsigned)(t >> 6);

    unsigned* h32 = (unsigned*)h8;
    for (int i = t; i < NWAVE * BINS / 4; i += HT) h32[i] = 0u;
    __syncthreads();

    const int4* __restrict__ p4 = (const int4*)prev;
    const int4* __restrict__ c4 = (const int4*)curr;
    const int base = blockIdx.x * (HT * PT) + t;

    int4 pc = p4[base], cc = c4[base];
#pragma unroll
    for (int j = 0; j < PT; ++j) {
        int4 pn = pc, cn = cc;
        if (j + 1 < PT) { pn = p4[base + (j + 1) * HT]; cn = c4[base + (j + 1) * HT]; }

        unsigned b0 = (unsigned)((pc.x << 6) | cc.x);
        unsigned b1 = (unsigned)((pc.y << 6) | cc.y);
        unsigned b2 = (unsigned)((pc.z << 6) | cc.z);
        unsigned b3 = (unsigned)((pc.w << 6) | cc.w);
        bool d0 = false, d1 = false, d2 = false, d3 = false;
        for (;;) {
            if (!d0) claimv[b0] = (unsigned)t;
            if (!d1) claimv[b1] = (unsigned)t;
            if (!d2) claimv[b2] = (unsigned)t;
            if (!d3) claimv[b3] = (unsigned)t;
            bool w0 = !d0 && (claimv[b0] == (unsigned)t);
            bool w1 = !d1 && (claimv[b1] == (unsigned)t);
            bool w2 = !d2 && (claimv[b2] == (unsigned)t);
            bool w3 = !d3 && (claimv[b3] == (unsigned)t);
            if (w0) { unsigned i0 = b0 * 8u + ((b0 + wave) & 7u); h8[i0] = (unsigned char)(h8[i0] + 1); d0 = true; }
            if (w1) { unsigned i1 = b1 * 8u + ((b1 + wave) & 7u); h8[i1] = (unsigned char)(h8[i1] + 1); d1 = true; }
            if (w2) { unsigned i2 = b2 * 8u + ((b2 + wave) & 7u); h8[i2] = (unsigned char)(h8[i2] + 1); d2 = true; }
            if (w3) { unsigned i3 = b3 * 8u + ((b3 + wave) & 7u); h8[i3] = (unsigned char)(h8[i3] + 1); d3 = true; }
            if (__ballot(!(d0 && d1 && d2 && d3)) == 0ull) break;
        }
        pc = pn; cc = cn;
    }

    __syncthreads();
    // merge the 8 per-wave u8 cells of each bin (swizzle is a permutation of
    // the 8-cell block) -> u32 partial row, plain coalesced stores
    for (int b = t; b < BINS; b += HT) {
        unsigned s = 0;
#pragma unroll
        for (int k = 0; k < 8; ++k) s += (unsigned)h8[b * 8 + k];
        ws[(size_t)blockIdx.x * BINS + b] = s;
    }
}

// 512 blocks: 16 bin-groups x 32 splits; each block sums 32 rows for 256 bins
// (coalesced), then one float atomicAdd per bin (depth 32 per address).
__global__ void __launch_bounds__(RED_THREADS)
topo_reduce_kernel(const unsigned* __restrict__ ws, float* __restrict__ out) {
    const int groups = BINS / RED_THREADS;            // 16
    const int bin_group = blockIdx.x % groups;
    const int split     = blockIdx.x / groups;        // 0..31
    const int bin = bin_group * RED_THREADS + threadIdx.x;
    const int rows = HB / RED_SPLITS;                 // 32
    const int r0 = split * rows;
    unsigned sum = 0;
#pragma unroll 8
    for (int j = 0; j < rows; j++)
        sum += ws[(size_t)(r0 + j) * BINS + bin];
    if (sum) atomicAdd(&out[bin], (float)sum);
}

// Fallback for arbitrary n / small ws (predicated, LDS-atomic).
__global__ void __launch_bounds__(512)
topo_hist_generic(const int* __restrict__ prev,
                  const int* __restrict__ curr,
                  float* __restrict__ out, int n) {
    __shared__ unsigned h[BINS];
    for (int i = threadIdx.x; i < BINS; i += 512) h[i] = 0u;
    __syncthreads();

    const int tid = blockIdx.x * 512 + threadIdx.x;
    const int stride = gridDim.x * 512;
    for (int i = tid; i < n; i += stride)
        atomicAdd(&h[(prev[i] << 6) | curr[i]], 1u);

    __syncthreads();
    for (int i = threadIdx.x; i < BINS; i += 512) {
        unsigned cnt = h[i];
        if (cnt) atomicAdd(&out[i], (float)cnt);
    }
}

extern "C" void kernel_launch(void* const* d_in, const int* in_sizes, int n_in,
                              void* d_out, int out_size, void* d_ws, size_t ws_size,
                              hipStream_t stream) {
    const int*   prev        = (const int*)d_in[0];
    const int*   curr        = (const int*)d_in[1];
    const float* transitions = (const float*)d_in[2];
    const float* total       = (const float*)d_in[3];
    float* out = (float*)d_out;

    const int n    = in_sizes[0];
    const int bins = in_sizes[2];   // 4096

    // 1) initialize output: copy transitions input, set total = total_in + n
    int init_blocks = (bins + 1 + 255) / 256;
    topo_init_kernel<<<init_blocks, 256, 0, stream>>>(transitions, total, out,
                                                      (float)n, bins);

    const long long exact_n  = (long long)HB * HT * PT * 4;
    const size_t    ws_needed = (size_t)HB * BINS * sizeof(unsigned);
    if (bins == BINS && (long long)n == exact_n && ws_size >= ws_needed) {
        // 2) atomic-free claim histogram -> per-block u32 partials in ws
        topo_hist_claim<<<HB, HT, 0, stream>>>(prev, curr, (unsigned*)d_ws);
        // 3) tree-reduce partials into out (atomic depth 32)
        topo_reduce_kernel<<<(BINS / RED_THREADS) * RED_SPLITS, RED_THREADS, 0,
                             stream>>>((unsigned*)d_ws, out);
    } else {
        topo_hist_generic<<<1024, 512, 0, stream>>>(prev, curr, out, n);
    }
}